// Round 5
// baseline (273.039 us; speedup 1.0000x reference)
//
#include <hip/hip_runtime.h>
#include <hip/hip_bf16.h>

// B=4, S=2048, D=1024.  M = B*S = 8192.
// Workspace layout (bytes):
//   [0,         33554432)  : E bf16 (4*2048*2048) = exp(scores)
//     overlay (dead before qk runs):
//     [0,         16777216) : Xb  bf16 (8192*1024)
//     [16777216,  23068672) : Wt  bf16 (3072*1024)
//   [50331648,  50364416)  : rowsum fp32 (8192)   (zeroed by setup)
//   [67108864,  83886080)  : Q bf16 (8192*1024)
//   [83886080, 100663296)  : K bf16 (8192*1024)
//   [100663296,117440512)  : Vt bf16 (4*1024*2048) -- written DIRECTLY by qkv
//
// Pipeline (4 launches):
//   setup  : cast X->bf16, transpose W->Wt bf16, zero rowsum
//   qkv    : single 1536-block dispatch, 128x128 4-wave drain core (~780TF,
//            MfmaUtil 32.5% ~= the m97-structure ceiling)
//   qk     : 64x128 tiles, 4-wave core, 1088 blocks + PACKED epilogue
//   pv     : 64x128 tiles, 4-wave core, 1024 blocks + PACKED epilogue
//
// R12 rationale: R4 (finer tiles, 4.25 blocks/CU) was NULL -- because the
// epilogue cost is tiling-invariant (32 values/thread at any tile shape;
// total scales with E bytes).  qk/pv epilogues were 32 scattered 2B/4B
// global stores per thread (MFMA C-layout -> 32B/64B segments), serialized
// at block end.  Fix: pack the output tile into the (dead) 24KB staging LDS
// with +pad stride, then fully-coalesced 16B/lane copies.  E: 64x136 bf16
// pack -> 8x short8 stores/thread.  out: two 32x132 f32 passes -> NT f32x4
// (out never re-read; NT only on out -- R3 proved NT on E regresses pv).
// Cores, grids, swizzles, masking, atomics unchanged from passing R4.

typedef __attribute__((ext_vector_type(8))) short short8;
typedef __attribute__((ext_vector_type(4))) short s16x4;
typedef __attribute__((ext_vector_type(4))) float f32x4;

__device__ __forceinline__ short f2bf(float f) {
  __hip_bfloat16 h = __float2bfloat16(f);
  return *reinterpret_cast<short*>(&h);
}

__device__ __forceinline__ void gll16(const void* g, void* l) {
  __builtin_amdgcn_global_load_lds((const __attribute__((address_space(1))) void*)g,
                                   (__attribute__((address_space(3))) void*)l,
                                   16, 0, 0);
}

__device__ __forceinline__ void ntst_f4(f32x4* p, f32x4 v) { __builtin_nontemporal_store(v, p); }

// ---------------------------------------------------------------------------
// 128x128-tile GEMM core, BK=64, 4 waves (qkv).  XOR bank swizzle on 16B
// k-groups (conflicts measured 0).
// ---------------------------------------------------------------------------
__device__ __forceinline__ void gemm_core(const short* __restrict__ A,
                                          const short* __restrict__ Bt,
                                          int lda, int ldb,
                                          int row0, int col0, int kIters,
                                          f32x4 acc[4][4],
                                          short* lA, short* lB) {
  const int tid  = threadIdx.x;
  const int wave = tid >> 6;
  const int lane = tid & 63;
  const int quad = lane >> 4;
  const int l16  = lane & 15;

  const f32x4 zero = {0.f, 0.f, 0.f, 0.f};
#pragma unroll
  for (int i = 0; i < 4; ++i)
#pragma unroll
    for (int j = 0; j < 4; ++j) acc[i][j] = zero;

  const int srow = tid >> 3;                    // 0..31
  const int gcol = ((tid & 7) ^ (srow & 7)) * 8;
  const short* A1 = A + (size_t)(row0 + srow) * lda + gcol;
  const short* A2 = A + (size_t)(row0 + srow + 32) * lda + gcol;
  const short* A3 = A + (size_t)(row0 + srow + 64) * lda + gcol;
  const short* A4 = A + (size_t)(row0 + srow + 96) * lda + gcol;
  const short* B1 = Bt + (size_t)(col0 + srow) * ldb + gcol;
  const short* B2 = Bt + (size_t)(col0 + srow + 32) * ldb + gcol;
  const short* B3 = Bt + (size_t)(col0 + srow + 64) * ldb + gcol;
  const short* B4 = Bt + (size_t)(col0 + srow + 96) * ldb + gcol;

  short* lA1 = lA + wave * 512;
  short* lA2 = lA + 2048 + wave * 512;
  short* lA3 = lA + 4096 + wave * 512;
  short* lA4 = lA + 6144 + wave * 512;
  short* lB1 = lB + wave * 512;
  short* lB2 = lB + 2048 + wave * 512;
  short* lB3 = lB + 4096 + wave * 512;
  short* lB4 = lB + 6144 + wave * 512;

  const int rswz  = l16 & 7;
  const int slot0 = (quad ^ rswz) * 8;
  const int slot1 = ((4 + quad) ^ rswz) * 8;
  const short* aRow = lA + ((wave >> 1) * 64 + l16) * 64;
  const short* bRow = lB + ((wave & 1) * 64 + l16) * 64;

  for (int it = 0; it < kIters; ++it) {
    const int k0 = it * 64;
    gll16(A1 + k0, lA1);
    gll16(A2 + k0, lA2);
    gll16(A3 + k0, lA3);
    gll16(A4 + k0, lA4);
    gll16(B1 + k0, lB1);
    gll16(B2 + k0, lB2);
    gll16(B3 + k0, lB3);
    gll16(B4 + k0, lB4);
    __syncthreads();

#pragma unroll
    for (int s = 0; s < 2; ++s) {
      const int so = s ? slot1 : slot0;
      short8 af[4], bfr[4];
#pragma unroll
      for (int i = 0; i < 4; ++i) af[i] = *(const short8*)(aRow + i * 1024 + so);
#pragma unroll
      for (int j = 0; j < 4; ++j) bfr[j] = *(const short8*)(bRow + j * 1024 + so);
#pragma unroll
      for (int i = 0; i < 4; ++i)
#pragma unroll
        for (int j = 0; j < 4; ++j)
          acc[i][j] = __builtin_amdgcn_mfma_f32_16x16x32_bf16(af[i], bfr[j], acc[i][j], 0, 0, 0);
    }
    __syncthreads();
  }
}

// ---------------------------------------------------------------------------
// 64x128-tile GEMM core, BK=64, 4 waves (qk/pv).  All waves share the 64
// A-rows; wave w owns output cols [w*32, w*32+32) -> acc[4][2].
// LDS: A 64x64 (8KB) + B 128x64 (16KB).  Proven swizzle: row r stores
// k-group g at slot g^(r&7) via the pre-swizzled global source (2-way=free).
// ---------------------------------------------------------------------------
__device__ __forceinline__ void gemm_core64(const short* __restrict__ A,
                                            const short* __restrict__ Bt,
                                            int lda, int ldb,
                                            int row0, int col0, int kIters,
                                            f32x4 acc[4][2],
                                            short* lA, short* lB) {
  const int tid  = threadIdx.x;
  const int wave = tid >> 6;
  const int lane = tid & 63;
  const int quad = lane >> 4;
  const int l16  = lane & 15;

  const f32x4 zero = {0.f, 0.f, 0.f, 0.f};
#pragma unroll
  for (int i = 0; i < 4; ++i)
#pragma unroll
    for (int j = 0; j < 2; ++j) acc[i][j] = zero;

  const int srow = tid >> 3;                    // 0..31
  const int gcol = ((tid & 7) ^ (srow & 7)) * 8;
  const short* A1 = A + (size_t)(row0 + srow) * lda + gcol;
  const short* A2 = A + (size_t)(row0 + srow + 32) * lda + gcol;
  const short* B1 = Bt + (size_t)(col0 + srow) * ldb + gcol;
  const short* B2 = Bt + (size_t)(col0 + srow + 32) * ldb + gcol;
  const short* B3 = Bt + (size_t)(col0 + srow + 64) * ldb + gcol;
  const short* B4 = Bt + (size_t)(col0 + srow + 96) * ldb + gcol;

  short* lA1 = lA + wave * 512;
  short* lA2 = lA + 2048 + wave * 512;
  short* lB1 = lB + wave * 512;
  short* lB2 = lB + 2048 + wave * 512;
  short* lB3 = lB + 4096 + wave * 512;
  short* lB4 = lB + 6144 + wave * 512;

  const int rswz  = l16 & 7;
  const int slot0 = (quad ^ rswz) * 8;
  const int slot1 = ((4 + quad) ^ rswz) * 8;
  const short* aRow = lA + l16 * 64;                 // rows i*16+l16, all waves
  const short* bRow = lB + (wave * 32 + l16) * 64;   // rows wave*32+j*16+l16

  for (int it = 0; it < kIters; ++it) {
    const int k0 = it * 64;
    gll16(A1 + k0, lA1);
    gll16(A2 + k0, lA2);
    gll16(B1 + k0, lB1);
    gll16(B2 + k0, lB2);
    gll16(B3 + k0, lB3);
    gll16(B4 + k0, lB4);
    __syncthreads();

#pragma unroll
    for (int s = 0; s < 2; ++s) {
      const int so = s ? slot1 : slot0;
      short8 af[4], bfr[2];
#pragma unroll
      for (int i = 0; i < 4; ++i) af[i] = *(const short8*)(aRow + i * 1024 + so);
#pragma unroll
      for (int j = 0; j < 2; ++j) bfr[j] = *(const short8*)(bRow + j * 1024 + so);
#pragma unroll
      for (int i = 0; i < 4; ++i)
#pragma unroll
        for (int j = 0; j < 2; ++j)
          acc[i][j] = __builtin_amdgcn_mfma_f32_16x16x32_bf16(af[i], bfr[j], acc[i][j], 0, 0, 0);
    }
    __syncthreads();
  }
}

// C/D layout: row = quad*4 + reg, col = l16  (verified m89)
#define EPILOGUE_VARS                         \
  const int lane = threadIdx.x & 63;          \
  const int wave = threadIdx.x >> 6;          \
  const int quad = lane >> 4;                 \
  const int l16  = lane & 15;                 \
  const int rb   = (wave >> 1) * 64;          \
  const int cb   = (wave & 1) * 64;

// ---------------------------------------------------------------------------
// setup: blocks [0,8192) cast X->Xb; [8192,11264) transpose W->Wt;
//        [11264,11272) zero rowsum.
__global__ __launch_bounds__(256) void setup_kernel(const float* __restrict__ X,
                                                    const float* __restrict__ W,
                                                    short* __restrict__ Xb,
                                                    short* __restrict__ Wt,
                                                    float* __restrict__ rs) {
  const int bid = blockIdx.x;
  if (bid < 8192) {
    const int i = (bid * 256 + threadIdx.x) * 4;
    const f32x4 v = *(const f32x4*)(X + i);
    s16x4 o;
    o.x = f2bf(v.x); o.y = f2bf(v.y); o.z = f2bf(v.z); o.w = f2bf(v.w);
    *(s16x4*)(Xb + i) = o;
  } else if (bid < 11264) {
    __shared__ float tile[32][33];
    const int r  = bid - 8192;
    const int ni = r % 96;
    const int ki = r / 96;
    const int tx = threadIdx.x & 31;
    const int ty = threadIdx.x >> 5;
#pragma unroll
    for (int rr = 0; rr < 4; ++rr)
      tile[ty + rr * 8][tx] = W[(size_t)(ki * 32 + ty + rr * 8) * 3072 + ni * 32 + tx];
    __syncthreads();
#pragma unroll
    for (int rr = 0; rr < 4; ++rr)
      Wt[(size_t)(ni * 32 + ty + rr * 8) * 1024 + ki * 32 + tx] = f2bf(tile[tx][ty + rr * 8]);
  } else {
    const int i = (bid - 11264) * 1024 + threadIdx.x * 4;
    const f32x4 zero = {0.f, 0.f, 0.f, 0.f};
    *(f32x4*)(rs + i) = zero;
  }
}

// QKV: [8192x1024] x Wt[3072x1024]^T, single 1536-block dispatch.
// Q,K row-major [s][d]; V-columns written transposed into Vt[b][d][s].
__global__ __launch_bounds__(256) void qkv_gemm_kernel(const short* __restrict__ Xb,
                                                       const short* __restrict__ Wt,
                                                       short* __restrict__ Q,
                                                       short* __restrict__ K,
                                                       short* __restrict__ Vt) {
  __shared__ short lA[8192], lB[8192];
  const int br = blockIdx.x / 24;
  const int bc = blockIdx.x % 24;
  f32x4 acc[4][4];
  gemm_core(Xb, Wt, 1024, 1024, br * 128, bc * 128, 16, acc, lA, lB);

  EPILOGUE_VARS
  const int rbase = br * 128 + rb;
  const int cbase = bc * 128 + cb;
  if (bc < 16) {
#pragma unroll
    for (int i = 0; i < 4; ++i)
#pragma unroll
      for (int j = 0; j < 4; ++j) {
        const int col = cbase + j * 16 + l16;
        short* dst = (col < 1024) ? Q : K;
        const int n = col & 1023;
#pragma unroll
        for (int r = 0; r < 4; ++r) {
          const int row = rbase + i * 16 + quad * 4 + r;
          dst[(size_t)row * 1024 + n] = f2bf(acc[i][j][r]);
        }
      }
  } else {
    const int b  = rbase >> 11;
    const int s0 = rbase & 2047;
    short* VtB = Vt + (size_t)b * 1024 * 2048;
#pragma unroll
    for (int i = 0; i < 4; ++i) {
      const int sb = s0 + i * 16 + quad * 4;
#pragma unroll
      for (int j = 0; j < 4; ++j) {
        const int d = cbase - 2048 + j * 16 + l16;
        s16x4 pk;
        pk.x = f2bf(acc[i][j][0]);
        pk.y = f2bf(acc[i][j][1]);
        pk.z = f2bf(acc[i][j][2]);
        pk.w = f2bf(acc[i][j][3]);
        *(s16x4*)(VtB + (size_t)d * 2048 + sb) = pk;
      }
    }
  }
}

// qk: 64x128 tiles, 4-wave core.  E = exp(QK^T/32) + rowsum atomics.
// Row-tile qi (64 rows) needs 128-col k-tiles ki=0..(qi>>1); the ki==qi>>1
// tile masks col>row (zero padding pv reads).  1088 blocks, bijective XCD
// chunk swizzle (1088 = 8*136).
// Epilogue: pack bf16 E-tile into LDS [64][136] (padded stride: scatter
// writes 2-way max), then fully-coalesced short8 copies to global.
__global__ __launch_bounds__(256) void qk_kernel(const short* __restrict__ Q,
                                                 const short* __restrict__ K,
                                                 short* __restrict__ E,
                                                 float* __restrict__ rs) {
  __shared__ __align__(16) short smem[12288];   // 24KB: core staging, then Epack
  const int orig = blockIdx.x;
  const int g = (orig & 7) * 136 + (orig >> 3);   // 1088 = 8*136, bijective
  const int t = g >> 2;    // 0..271
  const int b = g & 3;
  int qi = 31, off = t;
  while (off >= (qi >> 1) + 1) { off -= (qi >> 1) + 1; qi--; }  // qi desc
  const int ki = off;

  f32x4 acc[4][2];
  const short* Qb = Q + (size_t)b * 2048 * 1024;
  const short* Kb = K + (size_t)b * 2048 * 1024;
  gemm_core64(Qb, Kb, 1024, 1024, qi * 64, ki * 128, 16, acc, smem, smem + 4096);

  const int lane = threadIdx.x & 63;
  const int wave = threadIdx.x >> 6;
  const int quad = lane >> 4;
  const int l16  = lane & 15;
  short* Eb  = E + (size_t)b * 2048 * 2048;
  float* rsb = rs + b * 2048;
  const int rbase  = qi * 64;
  const int cbase0 = ki * 128;
  const bool diag = (ki == (qi >> 1));

  short* Epack = smem;   // 64*136 = 8704 shorts, fits; staging LDS is dead
#pragma unroll
  for (int i = 0; i < 4; ++i)
#pragma unroll
    for (int r = 0; r < 4; ++r) {
      const int lr  = i * 16 + quad * 4 + r;    // 0..63
      const int row = rbase + lr;
      float partial = 0.f;
#pragma unroll
      for (int j = 0; j < 2; ++j) {
        const int c   = wave * 32 + j * 16 + l16;   // 0..127
        const int col = cbase0 + c;
        float e = __expf(acc[i][j][r] * 0.03125f);
        if (diag && col > row) e = 0.f;
        partial += e;
        Epack[lr * 136 + c] = f2bf(e);
      }
      partial += __shfl_xor(partial, 1);
      partial += __shfl_xor(partial, 2);
      partial += __shfl_xor(partial, 4);
      partial += __shfl_xor(partial, 8);
      if (l16 == 0) atomicAdd(rsb + row, partial);
    }
  __syncthreads();
  {
    const int tt  = threadIdx.x;
    const int lr2 = tt >> 2;          // 0..63
    const int cs  = (tt & 3) * 32;    // 0,32,64,96
    const short* src = Epack + lr2 * 136 + cs;
    short* dst = Eb + (size_t)(rbase + lr2) * 2048 + cbase0 + cs;
#pragma unroll
    for (int u = 0; u < 4; ++u)
      *(short8*)(dst + u * 8) = *(const short8*)(src + u * 8);
  }
}

// pv: 64x128 out tiles, 4-wave core.  out = (E x V)/rowsum.  Row-tile qi
// has causal K-extent (qi+1)*64 -> kIters = qi+1 (E's masked zeros cover
// the diagonal remainder).  1024 blocks, bijective XCD chunk swizzle,
// heavy rows first.  Epilogue: two 32x132-f32 LDS pack passes -> NT f32x4
// coalesced stores (out is never re-read).
__global__ __launch_bounds__(256) void pv_kernel(const short* __restrict__ E,
                                                 const short* __restrict__ Vt,
                                                 const float* __restrict__ rs,
                                                 float* __restrict__ out) {
  __shared__ __align__(16) short smem[12288];
  const int orig = blockIdx.x;
  const int g = (orig & 7) * 128 + (orig >> 3);   // 1024 = 8*128, bijective
  const int t   = g >> 2;          // 0..255
  const int b   = g & 3;
  const int qi  = 31 - (t >> 3);   // heavy first
  const int dj  = t & 7;

  f32x4 acc[4][2];
  const short* Eb  = E + (size_t)b * 2048 * 2048;
  const short* Vtb = Vt + (size_t)b * 1024 * 2048;
  gemm_core64(Eb, Vtb, 2048, 2048, qi * 64, dj * 128, qi + 1, acc, smem, smem + 4096);

  const int lane = threadIdx.x & 63;
  const int wave = threadIdx.x >> 6;
  const int quad = lane >> 4;
  const int l16  = lane & 15;
  float* ob = out + (size_t)b * 2048 * 1024;
  const float* rsb = rs + b * 2048;
  const int rbase  = qi * 64;
  const int cbase0 = dj * 128;

  float* Opack = (float*)smem;   // 32*132 = 4224 f32 = 16.9KB, fits
#pragma unroll
  for (int p = 0; p < 2; ++p) {
#pragma unroll
    for (int i2 = 0; i2 < 2; ++i2) {
      const int i = p * 2 + i2;
#pragma unroll
      for (int r2 = 0; r2 < 4; ++r2) {
        const int lr  = i2 * 16 + quad * 4 + r2;       // 0..31 within pass
        const int row = rbase + p * 32 + lr;
        const float inv = 1.f / rsb[row];
#pragma unroll
        for (int j = 0; j < 2; ++j) {
          const int c = wave * 32 + j * 16 + l16;
          Opack[lr * 132 + c] = acc[i][j][r2] * inv;
        }
      }
    }
    __syncthreads();
    {
      const int tt = threadIdx.x;
      const int r3 = tt >> 3;           // 0..31
      const int cs = (tt & 7) * 16;     // 0..112
      const float* src = Opack + r3 * 132 + cs;
      float* dst = ob + (size_t)(rbase + p * 32 + r3) * 1024 + cbase0 + cs;
#pragma unroll
      for (int u = 0; u < 4; ++u)
        ntst_f4((f32x4*)(dst + u * 4), *(const f32x4*)(src + u * 4));
    }
    __syncthreads();
  }
}

// ---------------------------------------------------------------------------
extern "C" void kernel_launch(void* const* d_in, const int* in_sizes, int n_in,
                              void* d_out, int out_size, void* d_ws, size_t ws_size,
                              hipStream_t stream) {
  const float* X = (const float*)d_in[0];
  const float* W = (const float*)d_in[1];
  float* out = (float*)d_out;
  char* w = (char*)d_ws;

  short* Xb = (short*)(w + 0);
  short* Wt = (short*)(w + 16777216);
  short* E  = (short*)(w + 0);          // overlays Xb,Wt (dead after qkv)
  float* rs = (float*)(w + 50331648);
  short* Q  = (short*)(w + 67108864);
  short* K  = (short*)(w + 83886080);
  short* Vt = (short*)(w + 100663296);

  hipLaunchKernelGGL(setup_kernel,    dim3(11272), dim3(256), 0, stream, X, W, Xb, Wt, rs);
  hipLaunchKernelGGL(qkv_gemm_kernel, dim3(1536),  dim3(256), 0, stream, Xb, Wt, Q, K, Vt);
  hipLaunchKernelGGL(qk_kernel,       dim3(1088),  dim3(256), 0, stream, Q, K, E, rs);
  hipLaunchKernelGGL(pv_kernel,       dim3(1024),  dim3(256), 0, stream, E, Vt, rs, out);
}

// Round 6
// 243.929 us; speedup vs baseline: 1.1193x; 1.1193x over previous
//
#include <hip/hip_runtime.h>
#include <hip/hip_bf16.h>

// B=4, S=2048, D=1024.  M = B*S = 8192.
// Workspace layout (bytes):
//   [0,         33554432)  : E bf16 (4*2048*2048) = exp(scores)
//     overlay (dead before qk runs):
//     [0,         16777216) : Xb  bf16 (8192*1024)
//     [16777216,  23068672) : Wt  bf16 (3072*1024)
//   [50331648,  50364416)  : rowsum fp32 (8192)   (zeroed by setup)
//   [67108864,  83886080)  : Q bf16 (8192*1024)
//   [83886080, 100663296)  : K bf16 (8192*1024)
//   [100663296,117440512)  : Vt bf16 (4*1024*2048) -- written DIRECTLY by qkv
//
// Pipeline (4 launches):
//   setup  : cast X->bf16, transpose W->Wt bf16, zero rowsum
//   qkv    : 1536 blocks, 128x128 4-wave core, 32x32x16 MFMA (R13)
//   qk     : 64x128 tiles, 4-wave core, 1088 blocks (R4-proven)
//   pv     : 64x128 tiles, 4-wave core, 1024 blocks (R4-proven)
//
// R13 rationale: R5's packed/NT epilogues REGRESSED pv (WRITE_SIZE 33->88MB)
// -- reverted; NT line of attack closed.  qk/pv insensitivity across R1-R5
// matches the measured small-N shape curve (m102: ~320 TF at 2048-class
// shapes) -- structural, left alone.  qkv at MfmaUtil 32.5 + VALUBusy 38
// (~71% issue) is issue-pressure-bound: switch its core to 32x32x16 MFMA
// (halves MFMA+ds_read instruction counts per FLOP; ubench +15%).  C-layout
// col=lane&31, row=(reg&3)+8*(reg>>2)+4*(lane>>5) [m74/m101].  Staging,
// LDS layout, swizzle (measured 0 conflicts) unchanged.

typedef __attribute__((ext_vector_type(8))) short short8;
typedef __attribute__((ext_vector_type(4))) short s16x4;
typedef __attribute__((ext_vector_type(4))) float f32x4;
typedef __attribute__((ext_vector_type(16))) float f32x16;

__device__ __forceinline__ short f2bf(float f) {
  __hip_bfloat16 h = __float2bfloat16(f);
  return *reinterpret_cast<short*>(&h);
}

__device__ __forceinline__ void gll16(const void* g, void* l) {
  __builtin_amdgcn_global_load_lds((const __attribute__((address_space(1))) void*)g,
                                   (__attribute__((address_space(3))) void*)l,
                                   16, 0, 0);
}

__device__ __forceinline__ void ntst_f(float* p, float v) { __builtin_nontemporal_store(v, p); }

// ---------------------------------------------------------------------------
// 128x128-tile GEMM core, BK=64, 4 waves, 32x32x16 MFMA (qkv).
// Staging + XOR swizzle identical to the proven 16x16 core: LDS row r holds
// k-group g at slot g^(r&7) (2-way max, measured 0 conflicts).
// Wave quadrant 64x64 = 2x2 frags of 32x32; 4 k-steps of K=16 per iter.
// Fragment read: lane l (l32=l&31, hi=l>>5) reads row base+fi*32+l32,
// k-group g = ks*2+hi at slot (g^(l32&7))*8  (row&7 == l32&7: bases mult 8).
// ---------------------------------------------------------------------------
__device__ __forceinline__ void gemm_core3232(const short* __restrict__ A,
                                              const short* __restrict__ Bt,
                                              int lda, int ldb,
                                              int row0, int col0, int kIters,
                                              f32x16 acc[2][2],
                                              short* lA, short* lB) {
  const int tid  = threadIdx.x;
  const int wave = tid >> 6;
  const int lane = tid & 63;
  const int l32  = lane & 31;
  const int hi   = lane >> 5;

#pragma unroll
  for (int i = 0; i < 2; ++i)
#pragma unroll
    for (int j = 0; j < 2; ++j)
#pragma unroll
      for (int e = 0; e < 16; ++e) acc[i][j][e] = 0.f;

  const int srow = tid >> 3;                    // 0..31
  const int gcol = ((tid & 7) ^ (srow & 7)) * 8;
  const short* A1 = A + (size_t)(row0 + srow) * lda + gcol;
  const short* A2 = A + (size_t)(row0 + srow + 32) * lda + gcol;
  const short* A3 = A + (size_t)(row0 + srow + 64) * lda + gcol;
  const short* A4 = A + (size_t)(row0 + srow + 96) * lda + gcol;
  const short* B1 = Bt + (size_t)(col0 + srow) * ldb + gcol;
  const short* B2 = Bt + (size_t)(col0 + srow + 32) * ldb + gcol;
  const short* B3 = Bt + (size_t)(col0 + srow + 64) * ldb + gcol;
  const short* B4 = Bt + (size_t)(col0 + srow + 96) * ldb + gcol;

  short* lA1 = lA + wave * 512;
  short* lA2 = lA + 2048 + wave * 512;
  short* lA3 = lA + 4096 + wave * 512;
  short* lA4 = lA + 6144 + wave * 512;
  short* lB1 = lB + wave * 512;
  short* lB2 = lB + 2048 + wave * 512;
  short* lB3 = lB + 4096 + wave * 512;
  short* lB4 = lB + 6144 + wave * 512;

  const int rb = (wave >> 1) * 64;
  const int cb = (wave & 1) * 64;
  const short* aBase = lA + (rb + l32) * 64;
  const short* bBase = lB + (cb + l32) * 64;
  const int swz = l32 & 7;

  for (int it = 0; it < kIters; ++it) {
    const int k0 = it * 64;
    gll16(A1 + k0, lA1);
    gll16(A2 + k0, lA2);
    gll16(A3 + k0, lA3);
    gll16(A4 + k0, lA4);
    gll16(B1 + k0, lB1);
    gll16(B2 + k0, lB2);
    gll16(B3 + k0, lB3);
    gll16(B4 + k0, lB4);
    __syncthreads();

#pragma unroll
    for (int ks = 0; ks < 4; ++ks) {
      const int so = ((ks * 2 + hi) ^ swz) * 8;
      short8 a0 = *(const short8*)(aBase + so);
      short8 a1 = *(const short8*)(aBase + 2048 + so);
      short8 b0 = *(const short8*)(bBase + so);
      short8 b1 = *(const short8*)(bBase + 2048 + so);
      acc[0][0] = __builtin_amdgcn_mfma_f32_32x32x16_bf16(a0, b0, acc[0][0], 0, 0, 0);
      acc[0][1] = __builtin_amdgcn_mfma_f32_32x32x16_bf16(a0, b1, acc[0][1], 0, 0, 0);
      acc[1][0] = __builtin_amdgcn_mfma_f32_32x32x16_bf16(a1, b0, acc[1][0], 0, 0, 0);
      acc[1][1] = __builtin_amdgcn_mfma_f32_32x32x16_bf16(a1, b1, acc[1][1], 0, 0, 0);
    }
    __syncthreads();
  }
}

// ---------------------------------------------------------------------------
// 64x128-tile GEMM core, BK=64, 4 waves, 16x16x32 MFMA (qk/pv, R4-proven).
// ---------------------------------------------------------------------------
__device__ __forceinline__ void gemm_core64(const short* __restrict__ A,
                                            const short* __restrict__ Bt,
                                            int lda, int ldb,
                                            int row0, int col0, int kIters,
                                            f32x4 acc[4][2],
                                            short* lA, short* lB) {
  const int tid  = threadIdx.x;
  const int wave = tid >> 6;
  const int lane = tid & 63;
  const int quad = lane >> 4;
  const int l16  = lane & 15;

  const f32x4 zero = {0.f, 0.f, 0.f, 0.f};
#pragma unroll
  for (int i = 0; i < 4; ++i)
#pragma unroll
    for (int j = 0; j < 2; ++j) acc[i][j] = zero;

  const int srow = tid >> 3;                    // 0..31
  const int gcol = ((tid & 7) ^ (srow & 7)) * 8;
  const short* A1 = A + (size_t)(row0 + srow) * lda + gcol;
  const short* A2 = A + (size_t)(row0 + srow + 32) * lda + gcol;
  const short* B1 = Bt + (size_t)(col0 + srow) * ldb + gcol;
  const short* B2 = Bt + (size_t)(col0 + srow + 32) * ldb + gcol;
  const short* B3 = Bt + (size_t)(col0 + srow + 64) * ldb + gcol;
  const short* B4 = Bt + (size_t)(col0 + srow + 96) * ldb + gcol;

  short* lA1 = lA + wave * 512;
  short* lA2 = lA + 2048 + wave * 512;
  short* lB1 = lB + wave * 512;
  short* lB2 = lB + 2048 + wave * 512;
  short* lB3 = lB + 4096 + wave * 512;
  short* lB4 = lB + 6144 + wave * 512;

  const int rswz  = l16 & 7;
  const int slot0 = (quad ^ rswz) * 8;
  const int slot1 = ((4 + quad) ^ rswz) * 8;
  const short* aRow = lA + l16 * 64;                 // rows i*16+l16, all waves
  const short* bRow = lB + (wave * 32 + l16) * 64;   // rows wave*32+j*16+l16

  for (int it = 0; it < kIters; ++it) {
    const int k0 = it * 64;
    gll16(A1 + k0, lA1);
    gll16(A2 + k0, lA2);
    gll16(B1 + k0, lB1);
    gll16(B2 + k0, lB2);
    gll16(B3 + k0, lB3);
    gll16(B4 + k0, lB4);
    __syncthreads();

#pragma unroll
    for (int s = 0; s < 2; ++s) {
      const int so = s ? slot1 : slot0;
      short8 af[4], bfr[2];
#pragma unroll
      for (int i = 0; i < 4; ++i) af[i] = *(const short8*)(aRow + i * 1024 + so);
#pragma unroll
      for (int j = 0; j < 2; ++j) bfr[j] = *(const short8*)(bRow + j * 1024 + so);
#pragma unroll
      for (int i = 0; i < 4; ++i)
#pragma unroll
        for (int j = 0; j < 2; ++j)
          acc[i][j] = __builtin_amdgcn_mfma_f32_16x16x32_bf16(af[i], bfr[j], acc[i][j], 0, 0, 0);
    }
    __syncthreads();
  }
}

// ---------------------------------------------------------------------------
// setup: blocks [0,8192) cast X->Xb; [8192,11264) transpose W->Wt;
//        [11264,11272) zero rowsum.
__global__ __launch_bounds__(256) void setup_kernel(const float* __restrict__ X,
                                                    const float* __restrict__ W,
                                                    short* __restrict__ Xb,
                                                    short* __restrict__ Wt,
                                                    float* __restrict__ rs) {
  const int bid = blockIdx.x;
  if (bid < 8192) {
    const int i = (bid * 256 + threadIdx.x) * 4;
    const f32x4 v = *(const f32x4*)(X + i);
    s16x4 o;
    o.x = f2bf(v.x); o.y = f2bf(v.y); o.z = f2bf(v.z); o.w = f2bf(v.w);
    *(s16x4*)(Xb + i) = o;
  } else if (bid < 11264) {
    __shared__ float tile[32][33];
    const int r  = bid - 8192;
    const int ni = r % 96;
    const int ki = r / 96;
    const int tx = threadIdx.x & 31;
    const int ty = threadIdx.x >> 5;
#pragma unroll
    for (int rr = 0; rr < 4; ++rr)
      tile[ty + rr * 8][tx] = W[(size_t)(ki * 32 + ty + rr * 8) * 3072 + ni * 32 + tx];
    __syncthreads();
#pragma unroll
    for (int rr = 0; rr < 4; ++rr)
      Wt[(size_t)(ni * 32 + ty + rr * 8) * 1024 + ki * 32 + tx] = f2bf(tile[tx][ty + rr * 8]);
  } else {
    const int i = (bid - 11264) * 1024 + threadIdx.x * 4;
    const f32x4 zero = {0.f, 0.f, 0.f, 0.f};
    *(f32x4*)(rs + i) = zero;
  }
}

// QKV: [8192x1024] x Wt[3072x1024]^T, single 1536-block dispatch, 32x32 MFMA.
// Q,K row-major [s][d]; V-columns written transposed into Vt[b][d][s].
// C/D layout (m74/m101): col = lane&31, row = (reg&3)+8*(reg>>2)+4*(lane>>5).
__global__ __launch_bounds__(256) void qkv_gemm_kernel(const short* __restrict__ Xb,
                                                       const short* __restrict__ Wt,
                                                       short* __restrict__ Q,
                                                       short* __restrict__ K,
                                                       short* __restrict__ Vt) {
  __shared__ short lA[8192], lB[8192];
  const int br = blockIdx.x / 24;
  const int bc = blockIdx.x % 24;
  f32x16 acc[2][2];
  gemm_core3232(Xb, Wt, 1024, 1024, br * 128, bc * 128, 16, acc, lA, lB);

  const int lane = threadIdx.x & 63;
  const int wave = threadIdx.x >> 6;
  const int l32  = lane & 31;
  const int hi   = lane >> 5;
  const int rbase = br * 128 + (wave >> 1) * 64;
  const int cbase = bc * 128 + (wave & 1) * 64;

  if (bc < 16) {
#pragma unroll
    for (int fi = 0; fi < 2; ++fi)
#pragma unroll
      for (int fj = 0; fj < 2; ++fj) {
        const int col = cbase + fj * 32 + l32;
        short* dst = (col < 1024) ? Q : K;
        const int n = col & 1023;
#pragma unroll
        for (int reg = 0; reg < 16; ++reg) {
          const int row = rbase + fi * 32 + (reg & 3) + 8 * (reg >> 2) + 4 * hi;
          dst[(size_t)row * 1024 + n] = f2bf(acc[fi][fj][reg]);
        }
      }
  } else {
    const int b  = rbase >> 11;
    const int s0 = rbase & 2047;
    short* VtB = Vt + (size_t)b * 1024 * 2048;
#pragma unroll
    for (int fi = 0; fi < 2; ++fi)
#pragma unroll
      for (int fj = 0; fj < 2; ++fj) {
        const int d = cbase - 2048 + fj * 32 + l32;
#pragma unroll
        for (int g = 0; g < 4; ++g) {
          const int sb = s0 + fi * 32 + 8 * g + 4 * hi;   // 4 consecutive s-rows
          s16x4 pk;
          pk.x = f2bf(acc[fi][fj][4 * g + 0]);
          pk.y = f2bf(acc[fi][fj][4 * g + 1]);
          pk.z = f2bf(acc[fi][fj][4 * g + 2]);
          pk.w = f2bf(acc[fi][fj][4 * g + 3]);
          *(s16x4*)(VtB + (size_t)d * 2048 + sb) = pk;
        }
      }
  }
}

// qk: 64x128 tiles, 4-wave core (R4-proven).  E = exp(QK^T/32) + rowsum
// atomics.  Row-tile qi needs 128-col k-tiles ki=0..(qi>>1); ki==qi>>1
// masks col>row (zero padding pv reads).  1088 blocks, bijective XCD
// chunk swizzle (1088 = 8*136).
__global__ __launch_bounds__(256) void qk_kernel(const short* __restrict__ Q,
                                                 const short* __restrict__ K,
                                                 short* __restrict__ E,
                                                 float* __restrict__ rs) {
  __shared__ short lA[4096], lB[8192];
  const int orig = blockIdx.x;
  const int g = (orig & 7) * 136 + (orig >> 3);   // 1088 = 8*136, bijective
  const int t = g >> 2;    // 0..271
  const int b = g & 3;
  int qi = 31, off = t;
  while (off >= (qi >> 1) + 1) { off -= (qi >> 1) + 1; qi--; }  // qi desc
  const int ki = off;

  f32x4 acc[4][2];
  const short* Qb = Q + (size_t)b * 2048 * 1024;
  const short* Kb = K + (size_t)b * 2048 * 1024;
  gemm_core64(Qb, Kb, 1024, 1024, qi * 64, ki * 128, 16, acc, lA, lB);

  const int lane = threadIdx.x & 63;
  const int wave = threadIdx.x >> 6;
  const int quad = lane >> 4;
  const int l16  = lane & 15;
  short* Eb  = E + (size_t)b * 2048 * 2048;
  float* rsb = rs + b * 2048;
  const int rbase = qi * 64;
  const int cbase = ki * 128 + wave * 32;
  const bool diag = (ki == (qi >> 1));
#pragma unroll
  for (int i = 0; i < 4; ++i)
#pragma unroll
    for (int r = 0; r < 4; ++r) {
      const int row = rbase + i * 16 + quad * 4 + r;
      float partial = 0.f;
#pragma unroll
      for (int j = 0; j < 2; ++j) {
        const int col = cbase + j * 16 + l16;
        float e = __expf(acc[i][j][r] * 0.03125f);
        if (diag && col > row) e = 0.f;
        partial += e;
        Eb[(size_t)row * 2048 + col] = f2bf(e);
      }
      partial += __shfl_xor(partial, 1);
      partial += __shfl_xor(partial, 2);
      partial += __shfl_xor(partial, 4);
      partial += __shfl_xor(partial, 8);
      if (l16 == 0) atomicAdd(rsb + row, partial);
    }
}

// pv: 64x128 out tiles, 4-wave core (R4-proven).  out = (E x V)/rowsum.
// Row-tile qi has causal K-extent (qi+1)*64 -> kIters = qi+1.  1024 blocks,
// bijective XCD chunk swizzle, heavy rows first.
__global__ __launch_bounds__(256) void pv_kernel(const short* __restrict__ E,
                                                 const short* __restrict__ Vt,
                                                 const float* __restrict__ rs,
                                                 float* __restrict__ out) {
  __shared__ short lA[4096], lB[8192];
  const int orig = blockIdx.x;
  const int g = (orig & 7) * 128 + (orig >> 3);   // 1024 = 8*128, bijective
  const int t   = g >> 2;          // 0..255
  const int b   = g & 3;
  const int qi  = 31 - (t >> 3);   // heavy first
  const int dj  = t & 7;

  f32x4 acc[4][2];
  const short* Eb  = E + (size_t)b * 2048 * 2048;
  const short* Vtb = Vt + (size_t)b * 1024 * 2048;
  gemm_core64(Eb, Vtb, 2048, 2048, qi * 64, dj * 128, qi + 1, acc, lA, lB);

  const int lane = threadIdx.x & 63;
  const int wave = threadIdx.x >> 6;
  const int quad = lane >> 4;
  const int l16  = lane & 15;
  float* ob = out + (size_t)b * 2048 * 1024;
  const float* rsb = rs + b * 2048;
  const int rbase = qi * 64;
  const int cbase = dj * 128 + wave * 32;
#pragma unroll
  for (int i = 0; i < 4; ++i)
#pragma unroll
    for (int r2 = 0; r2 < 4; ++r2) {
      const int row = rbase + i * 16 + quad * 4 + r2;
      const float inv = 1.f / rsb[row];
#pragma unroll
      for (int j = 0; j < 2; ++j) {
        const int col = cbase + j * 16 + l16;
        ntst_f(&ob[(size_t)row * 1024 + col], acc[i][j][r2] * inv);
      }
    }
}

// ---------------------------------------------------------------------------
extern "C" void kernel_launch(void* const* d_in, const int* in_sizes, int n_in,
                              void* d_out, int out_size, void* d_ws, size_t ws_size,
                              hipStream_t stream) {
  const float* X = (const float*)d_in[0];
  const float* W = (const float*)d_in[1];
  float* out = (float*)d_out;
  char* w = (char*)d_ws;

  short* Xb = (short*)(w + 0);
  short* Wt = (short*)(w + 16777216);
  short* E  = (short*)(w + 0);          // overlays Xb,Wt (dead after qkv)
  float* rs = (float*)(w + 50331648);
  short* Q  = (short*)(w + 67108864);
  short* K  = (short*)(w + 83886080);
  short* Vt = (short*)(w + 100663296);

  hipLaunchKernelGGL(setup_kernel,    dim3(11272), dim3(256), 0, stream, X, W, Xb, Wt, rs);
  hipLaunchKernelGGL(qkv_gemm_kernel, dim3(1536),  dim3(256), 0, stream, Xb, Wt, Q, K, Vt);
  hipLaunchKernelGGL(qk_kernel,       dim3(1088),  dim3(256), 0, stream, Q, K, E, rs);
  hipLaunchKernelGGL(pv_kernel,       dim3(1024),  dim3(256), 0, stream, E, Vt, rs, out);
}